// Round 1
// baseline (1011.287 us; speedup 1.0000x reference)
//
#include <hip/hip_runtime.h>
#include <math.h>

#define HID 64
#define NBATCH 500000

__device__ __forceinline__ float fast_tanh(float x) {
    // tanh(x) = 1 - 2/(exp(2x)+1); exp overflow -> inf -> rcp -> 0 -> 1 (correct)
    float e = __expf(2.0f * x);
    return 1.0f - 2.0f * __builtin_amdgcn_rcpf(e + 1.0f);
}

// ---- E_des pre-kernel: one wave, computed once into d_ws[0] ----
__global__ void edes_kernel(const float* __restrict__ W1, const float* __restrict__ b1,
                            const float* __restrict__ W2, const float* __restrict__ b2,
                            const float* __restrict__ W3, const float* __restrict__ b3,
                            const float* __restrict__ x0, float* __restrict__ out) {
    int j = threadIdx.x;  // 0..63
    float q1 = x0[0], q2 = x0[1], p1 = x0[2], p2 = x0[3];

    // each lane redundantly computes full h1 (trivial work)
    float h1[HID];
#pragma unroll
    for (int i = 0; i < HID; i++)
        h1[i] = fast_tanh(fmaf(q1, W1[i], fmaf(q2, W1[HID + i], b1[i])));

    // lane j owns h2[j]; W2[i*HID+j] is a coalesced row read per i
    float z = b2[j];
#pragma unroll
    for (int i = 0; i < HID; i++)
        z = fmaf(h1[i], W2[i * HID + j], z);
    float h2 = fast_tanh(z);
    float v = h2 * W3[j];
#pragma unroll
    for (int off = 32; off; off >>= 1) v += __shfl_xor(v, off, 64);

    if (j == 0) {
        float V = v + b3[0];
        float s, c;
        __sincosf(q2, &s, &c);
        float DEN = 2.0f - c * c;
        float rDEN = __builtin_amdgcn_rcpf(DEN);
        float quad = (p1 * p1 - 2.0f * (c + 1.0f) * p1 * p2 + (2.0f * c + 3.0f) * p2 * p2) * rDEN;
        float kin = 0.5f * quad;
        float s1, c1;
        __sincosf(q1, &s1, &c1);
        float c12 = c1 * c - s1 * s;
        float dq = 1.57079632679489662f - q2;
        float pot = -9.81f * (c12 + 2.0f * c1) + 0.5f * dq * dq;
        out[0] = pot + kin + V;
    }
}

// ---- Main kernel: one thread per batch element ----
__global__ __launch_bounds__(256) void pend_kernel(
    const float4* __restrict__ x,
    const float* __restrict__ W1, const float* __restrict__ b1,
    const float* __restrict__ W2, const float* __restrict__ b2,
    const float* __restrict__ W3, const float* __restrict__ b3,
    const float* __restrict__ Tp, const float* __restrict__ edes_p,
    float4* __restrict__ out, int n)
{
    int t = blockIdx.x * blockDim.x + threadIdx.x;
    if (t >= n) return;

    float4 xv = x[t];
    float q1 = xv.x, q2 = xv.y, p1 = xv.z, p2 = xv.w;
    float E_des = edes_p[0];
    float Tabs = fabsf(Tp[0]);

    // ---- layer 1: h1[j] = tanh(q1*W1[0][j] + q2*W1[1][j] + b1[j]) ----
    float h1[HID];
#pragma unroll
    for (int j = 0; j < HID; j++)
        h1[j] = fast_tanh(fmaf(q1, W1[j], fmaf(q2, W1[HID + j], b1[j])));

    // ---- layer 2 forward: acc[j] = sum_i h1[i]*W2[i][j] + b2[j] ----
    float acc[HID];
#pragma unroll
    for (int j = 0; j < HID; j++) acc[j] = b2[j];
#pragma unroll
    for (int i = 0; i < HID; i++) {
        float h = h1[i];
#pragma unroll
        for (int j = 0; j < HID; j++)
            acc[j] = fmaf(h, W2[i * HID + j], acc[j]);
    }

    // ---- V and g2 (reuse acc as g2[j] = W3[j]*(1-h2^2)) ----
    float vp0 = 0.f, vp1 = 0.f, vp2 = 0.f, vp3 = 0.f;
#pragma unroll
    for (int j = 0; j < HID; j += 4) {
        float a0 = fast_tanh(acc[j + 0]);
        float a1 = fast_tanh(acc[j + 1]);
        float a2 = fast_tanh(acc[j + 2]);
        float a3 = fast_tanh(acc[j + 3]);
        vp0 = fmaf(a0, W3[j + 0], vp0);
        vp1 = fmaf(a1, W3[j + 1], vp1);
        vp2 = fmaf(a2, W3[j + 2], vp2);
        vp3 = fmaf(a3, W3[j + 3], vp3);
        acc[j + 0] = W3[j + 0] * (1.0f - a0 * a0);
        acc[j + 1] = W3[j + 1] * (1.0f - a1 * a1);
        acc[j + 2] = W3[j + 2] * (1.0f - a2 * a2);
        acc[j + 3] = W3[j + 3] * (1.0f - a3 * a3);
    }
    float V = b3[0] + ((vp0 + vp1) + (vp2 + vp3));

    // ---- backward: gi = (1-h1[i]^2) * sum_j W2[i][j]*g2[j]; dVdq = W1^T g1 ----
    float dVq1 = 0.0f, dVq2 = 0.0f;
#pragma unroll
    for (int i = 0; i < HID; i++) {
        float s0 = 0.f, s1 = 0.f, s2 = 0.f, s3 = 0.f;
#pragma unroll
        for (int j = 0; j < HID; j += 4) {
            s0 = fmaf(W2[i * HID + j + 0], acc[j + 0], s0);
            s1 = fmaf(W2[i * HID + j + 1], acc[j + 1], s1);
            s2 = fmaf(W2[i * HID + j + 2], acc[j + 2], s2);
            s3 = fmaf(W2[i * HID + j + 3], acc[j + 3], s3);
        }
        float gi = (1.0f - h1[i] * h1[i]) * ((s0 + s1) + (s2 + s3));
        dVq1 = fmaf(W1[i],       gi, dVq1);
        dVq2 = fmaf(W1[HID + i], gi, dVq2);
    }

    // ---- physics (L1=L2=M1=M2=1, G=9.81, K1=0.5, A_E=1, B_DAMP=0) ----
    float s2q, c2q, s1q, c1q;
    __sincosf(q2, &s2q, &c2q);
    __sincosf(q1, &s1q, &c1q);
    float s12 = s1q * c2q + c1q * s2q;
    float c12 = c1q * c2q - s1q * s2q;

    float c = c2q, s = s2q;
    float DEN = 2.0f - c * c;            // == 1 + s^2
    float rDEN = __builtin_amdgcn_rcpf(DEN);
    float cp1 = c + 1.0f;

    float quad = (p1 * p1 - 2.0f * cp1 * p1 * p2 + (2.0f * c + 3.0f) * p2 * p2) * rDEN;
    float kin = 0.5f * quad;
    float dqa = 1.57079632679489662f - q2;
    float pot = -9.81f * (c12 + 2.0f * c1q) + 0.5f * dqa * dqa;
    float E = pot + kin + V;

    float fac = (quad > 0.0f) ? __builtin_amdgcn_rsqf(quad) : 1.0f;
    float coef = E_des - E;
    float u1 = -dVq1 + coef * p1 * fac;
    float u2 = -dVq2 + coef * p2 * fac;

    float dq1dt = (p1 - cp1 * p2) * rDEN;
    float dq2dt = ((2.0f * c + 3.0f) * p2 - cp1 * p1) * rDEN;
    float dp1dt = -9.81f * (s12 + 2.0f * s1q) + u1;

    float inner = -p2 * p2 * s * cp1 * (c + 2.0f)
                + p1 * p2 * s * (fmaf(c, c, fmaf(2.0f, c, 2.0f)))
                - c * p1 * p1 * s
                + DEN * DEN * (fmaf(9.81f, s12, -0.5f * (3.14159265358979324f - 2.0f * q2)));
    float dp2dt = -(inner * rDEN * rDEN) + u2;

    float4 o;
    o.x = Tabs * dq1dt;
    o.y = Tabs * dq2dt;
    o.z = Tabs * dp1dt;
    o.w = Tabs * dp2dt;
    out[t] = o;
}

extern "C" void kernel_launch(void* const* d_in, const int* in_sizes, int n_in,
                              void* d_out, int out_size, void* d_ws, size_t ws_size,
                              hipStream_t stream) {
    const float* x  = (const float*)d_in[0];
    // d_in[1] = t (unused)
    const float* W1 = (const float*)d_in[2];
    const float* b1 = (const float*)d_in[3];
    const float* W2 = (const float*)d_in[4];
    const float* b2 = (const float*)d_in[5];
    const float* W3 = (const float*)d_in[6];
    const float* b3 = (const float*)d_in[7];
    const float* Tp = (const float*)d_in[8];
    const float* x0 = (const float*)d_in[9];

    float* edes = (float*)d_ws;
    edes_kernel<<<1, 64, 0, stream>>>(W1, b1, W2, b2, W3, b3, x0, edes);

    int n = in_sizes[0] / 4;  // 500000
    int blocks = (n + 255) / 256;
    pend_kernel<<<blocks, 256, 0, stream>>>((const float4*)x, W1, b1, W2, b2, W3, b3,
                                            Tp, edes, (float4*)d_out, n);
}

// Round 2
// 129.675 us; speedup vs baseline: 7.7986x; 7.7986x over previous
//
#include <hip/hip_runtime.h>
#include <math.h>

#define HID 64

__device__ __forceinline__ float fast_tanh(float x) {
    // tanh(x) = 1 - 2/(exp(2x)+1); exp overflow -> inf -> rcp -> 0 -> 1 (correct)
    float e = __expf(2.0f * x);
    return 1.0f - 2.0f * __builtin_amdgcn_rcpf(e + 1.0f);
}

// ---- E_des pre-kernel: one wave, computed once into d_ws[0] ----
__global__ void edes_kernel(const float* __restrict__ W1, const float* __restrict__ b1,
                            const float* __restrict__ W2, const float* __restrict__ b2,
                            const float* __restrict__ W3, const float* __restrict__ b3,
                            const float* __restrict__ x0, float* __restrict__ out) {
    int j = threadIdx.x;  // 0..63
    float q1 = x0[0], q2 = x0[1], p1 = x0[2], p2 = x0[3];

    // lane j owns hidden unit j end-to-end
    float h1j = fast_tanh(fmaf(q1, W1[j], fmaf(q2, W1[HID + j], b1[j])));

    // z2[j] = sum_i h1[i] * W2[i][j]; broadcast h1[i] via shfl
    float z = b2[j];
#pragma unroll 1
    for (int i = 0; i < HID; i++) {
        float hi = __shfl(h1j, i, 64);
        z = fmaf(hi, W2[i * HID + j], z);
    }
    float h2 = fast_tanh(z);
    float v = h2 * W3[j];
#pragma unroll
    for (int off = 32; off; off >>= 1) v += __shfl_xor(v, off, 64);

    if (j == 0) {
        float V = v + b3[0];
        float s, c;
        __sincosf(q2, &s, &c);
        float DEN = 2.0f - c * c;
        float rDEN = __builtin_amdgcn_rcpf(DEN);
        float quad = (p1 * p1 - 2.0f * (c + 1.0f) * p1 * p2 + (2.0f * c + 3.0f) * p2 * p2) * rDEN;
        float kin = 0.5f * quad;
        float s1, c1;
        __sincosf(q1, &s1, &c1);
        float c12 = c1 * c - s1 * s;
        float dq = 1.57079632679489662f - q2;
        float pot = -9.81f * (c12 + 2.0f * c1) + 0.5f * dq * dq;
        out[0] = pot + kin + V;
    }
}

// ---- Main kernel: one thread per batch element; i-loops are REAL loops ----
__global__ __launch_bounds__(256, 4) void pend_kernel(
    const float4* __restrict__ x,
    const float* __restrict__ W1, const float* __restrict__ b1,
    const float* __restrict__ W2, const float* __restrict__ b2,
    const float* __restrict__ W3, const float* __restrict__ b3,
    const float* __restrict__ Tp, const float* __restrict__ edes_p,
    float4* __restrict__ out, int n)
{
    int t = blockIdx.x * blockDim.x + threadIdx.x;
    if (t >= n) return;

    float4 xv = x[t];
    float q1 = xv.x, q2 = xv.y, p1 = xv.z, p2 = xv.w;
    float E_des = edes_p[0];
    float Tabs = fabsf(Tp[0]);

    // ---- layer 2 forward, layer 1 fused (h1[i] recomputed per i) ----
    float acc[HID];
#pragma unroll
    for (int j = 0; j < HID; j++) acc[j] = b2[j];

#pragma unroll 1
    for (int i = 0; i < HID; i++) {
        float h = fast_tanh(fmaf(q1, W1[i], fmaf(q2, W1[HID + i], b1[i])));
        const float* w2row = W2 + i * HID;   // wave-uniform address -> s_load rows
#pragma unroll
        for (int j = 0; j < HID; j++)
            acc[j] = fmaf(h, w2row[j], acc[j]);
    }

    // ---- V and g2 (reuse acc as g2[j] = W3[j]*(1-h2^2)) ----
    float vp0 = 0.f, vp1 = 0.f, vp2 = 0.f, vp3 = 0.f;
#pragma unroll
    for (int j = 0; j < HID; j += 4) {
        float a0 = fast_tanh(acc[j + 0]);
        float a1 = fast_tanh(acc[j + 1]);
        float a2 = fast_tanh(acc[j + 2]);
        float a3 = fast_tanh(acc[j + 3]);
        vp0 = fmaf(a0, W3[j + 0], vp0);
        vp1 = fmaf(a1, W3[j + 1], vp1);
        vp2 = fmaf(a2, W3[j + 2], vp2);
        vp3 = fmaf(a3, W3[j + 3], vp3);
        acc[j + 0] = W3[j + 0] * (1.0f - a0 * a0);
        acc[j + 1] = W3[j + 1] * (1.0f - a1 * a1);
        acc[j + 2] = W3[j + 2] * (1.0f - a2 * a2);
        acc[j + 3] = W3[j + 3] * (1.0f - a3 * a3);
    }
    float V = b3[0] + ((vp0 + vp1) + (vp2 + vp3));

    // ---- backward: gi = (1-h1[i]^2) * sum_j W2[i][j]*g2[j]; dVdq = W1^T g1 ----
    float dVq1 = 0.0f, dVq2 = 0.0f;
#pragma unroll 1
    for (int i = 0; i < HID; i++) {
        float h = fast_tanh(fmaf(q1, W1[i], fmaf(q2, W1[HID + i], b1[i])));
        const float* w2row = W2 + i * HID;
        float s0 = 0.f, s1 = 0.f, s2 = 0.f, s3 = 0.f;
#pragma unroll
        for (int j = 0; j < HID; j += 4) {
            s0 = fmaf(w2row[j + 0], acc[j + 0], s0);
            s1 = fmaf(w2row[j + 1], acc[j + 1], s1);
            s2 = fmaf(w2row[j + 2], acc[j + 2], s2);
            s3 = fmaf(w2row[j + 3], acc[j + 3], s3);
        }
        float gi = (1.0f - h * h) * ((s0 + s1) + (s2 + s3));
        dVq1 = fmaf(W1[i],       gi, dVq1);
        dVq2 = fmaf(W1[HID + i], gi, dVq2);
    }

    // ---- physics (L1=L2=M1=M2=1, G=9.81, K1=0.5, A_E=1, B_DAMP=0) ----
    float s2q, c2q, s1q, c1q;
    __sincosf(q2, &s2q, &c2q);
    __sincosf(q1, &s1q, &c1q);
    float s12 = s1q * c2q + c1q * s2q;
    float c12 = c1q * c2q - s1q * s2q;

    float c = c2q, s = s2q;
    float DEN = 2.0f - c * c;            // == 1 + s^2
    float rDEN = __builtin_amdgcn_rcpf(DEN);
    float cp1 = c + 1.0f;

    float quad = (p1 * p1 - 2.0f * cp1 * p1 * p2 + (2.0f * c + 3.0f) * p2 * p2) * rDEN;
    float kin = 0.5f * quad;
    float dqa = 1.57079632679489662f - q2;
    float pot = -9.81f * (c12 + 2.0f * c1q) + 0.5f * dqa * dqa;
    float E = pot + kin + V;

    float fac = (quad > 0.0f) ? __builtin_amdgcn_rsqf(quad) : 1.0f;
    float coef = E_des - E;
    float u1 = -dVq1 + coef * p1 * fac;
    float u2 = -dVq2 + coef * p2 * fac;

    float dq1dt = (p1 - cp1 * p2) * rDEN;
    float dq2dt = ((2.0f * c + 3.0f) * p2 - cp1 * p1) * rDEN;
    float dp1dt = -9.81f * (s12 + 2.0f * s1q) + u1;

    float inner = -p2 * p2 * s * cp1 * (c + 2.0f)
                + p1 * p2 * s * (fmaf(c, c, fmaf(2.0f, c, 2.0f)))
                - c * p1 * p1 * s
                + DEN * DEN * (fmaf(9.81f, s12, -0.5f * (3.14159265358979324f - 2.0f * q2)));
    float dp2dt = -(inner * rDEN * rDEN) + u2;

    float4 o;
    o.x = Tabs * dq1dt;
    o.y = Tabs * dq2dt;
    o.z = Tabs * dp1dt;
    o.w = Tabs * dp2dt;
    out[t] = o;
}

extern "C" void kernel_launch(void* const* d_in, const int* in_sizes, int n_in,
                              void* d_out, int out_size, void* d_ws, size_t ws_size,
                              hipStream_t stream) {
    const float* x  = (const float*)d_in[0];
    // d_in[1] = t (unused)
    const float* W1 = (const float*)d_in[2];
    const float* b1 = (const float*)d_in[3];
    const float* W2 = (const float*)d_in[4];
    const float* b2 = (const float*)d_in[5];
    const float* W3 = (const float*)d_in[6];
    const float* b3 = (const float*)d_in[7];
    const float* Tp = (const float*)d_in[8];
    const float* x0 = (const float*)d_in[9];

    float* edes = (float*)d_ws;
    edes_kernel<<<1, 64, 0, stream>>>(W1, b1, W2, b2, W3, b3, x0, edes);

    int n = in_sizes[0] / 4;  // 500000
    int blocks = (n + 255) / 256;
    pend_kernel<<<blocks, 256, 0, stream>>>((const float4*)x, W1, b1, W2, b2, W3, b3,
                                            Tp, edes, (float4*)d_out, n);
}